// Round 1
// baseline (207.026 us; speedup 1.0000x reference)
//
#include <hip/hip_runtime.h>

// Conv2D 15x15 valid cross-correlation, 4096x4096 fp32 -> 4082x4082 fp32.
// Round 0: fp32 LDS-tiled, register row-sliding kernel.
//
// Block: 256 threads -> 64(x) x 128(y) output tile. Each thread: 4x8 outputs.
// Input tile (78 x 142 floats, padded to 80-wide = 44.4 KB) staged in LDS.
// Per LDS input row a thread reads 20 floats (5x ds_read_b128) and applies
// them to every (kh, output-row) pair that consumes that row: 110 b128 reads
// vs 7200 v_fma_f32 per thread -> FMA-issue bound, LDS pipe ~37% loaded.
// Weights are wave-uniform -> scalar loads via K$.

#define HIN 4096
#define WIN 4096
#define KH 15
#define KW 15
#define OH (HIN - KH + 1)  // 4082
#define OW (WIN - KW + 1)  // 4082

#define BX 64
#define BY 128
#define TX 4
#define TY 8
#define NTX (BX / TX)          // 16 threads along x
#define NTY (BY / TY)          // 16 threads along y
#define LDSW 80                // 78 needed, pad to 80 (float4-aligned rows)
#define LDSH (BY + KH - 1)     // 142

__global__ __launch_bounds__(256, 3)
void conv2d_f32_tiled(const float* __restrict__ x,
                      const float* __restrict__ w,
                      const float* __restrict__ bias,
                      float* __restrict__ out) {
    __shared__ float tile[LDSH * LDSW];

    const int tid = threadIdx.x;
    const int bx0 = blockIdx.x * BX;
    const int by0 = blockIdx.y * BY;

    // ---------------- stage input tile: global -> LDS ----------------
    // 142 rows x 20 float4 = 2840 float4 slots; 256 threads, ~11 each.
    const int nslots = LDSH * (LDSW / 4);
    for (int f = tid; f < nslots; f += 256) {
        const int r  = f / (LDSW / 4);
        const int c4 = f - r * (LDSW / 4);
        int gy = by0 + r;
        if (gy > HIN - 1) gy = HIN - 1;          // clamp rows (values unused by valid outputs)
        const int gx = bx0 + c4 * 4;
        float4 v;
        if (gx + 3 <= WIN - 1) {
            v = *reinterpret_cast<const float4*>(&x[(size_t)gy * WIN + gx]);
        } else {
            const float* row = &x[(size_t)gy * WIN];
            const int x0 = min(gx + 0, WIN - 1);
            const int x1 = min(gx + 1, WIN - 1);
            const int x2 = min(gx + 2, WIN - 1);
            const int x3 = min(gx + 3, WIN - 1);
            v = make_float4(row[x0], row[x1], row[x2], row[x3]);
        }
        *reinterpret_cast<float4*>(&tile[r * LDSW + c4 * 4]) = v;
    }
    __syncthreads();

    // ---------------- compute: 4x8 register tile per thread ----------------
    const int tx  = tid & (NTX - 1);
    const int ty  = tid >> 4;
    const int lx0 = tx * TX;   // local col of first output
    const int ly0 = ty * TY;   // local row of first output

    float acc[TY][TX];
#pragma unroll
    for (int i = 0; i < TY; ++i)
#pragma unroll
        for (int j = 0; j < TX; ++j) acc[i][j] = 0.f;

    // Input rows this thread consumes: ly0 .. ly0 + TY + KH - 2  (22 rows)
    for (int r = 0; r < TY + KH - 1; ++r) {
        float buf[TX + 16];  // 20 floats: window [lx0, lx0+19]
        const float* lrow = &tile[(ly0 + r) * LDSW + lx0];
#pragma unroll
        for (int q = 0; q < 5; ++q) {
            const float4 v = *reinterpret_cast<const float4*>(&lrow[q * 4]);
            buf[q * 4 + 0] = v.x;
            buf[q * 4 + 1] = v.y;
            buf[q * 4 + 2] = v.z;
            buf[q * 4 + 3] = v.w;
        }
        // Input row (ly0 + r) feeds output row (ly0 + i) with kh = r - i.
#pragma unroll
        for (int i = 0; i < TY; ++i) {
            const int kh = r - i;
            if (kh >= 0 && kh < KH) {          // wave-uniform guard
                const float* wrow = &w[kh * KW];
#pragma unroll
                for (int kw = 0; kw < KW; ++kw) {
                    const float wv = wrow[kw];  // uniform -> s_load (K$)
#pragma unroll
                    for (int j = 0; j < TX; ++j)
                        acc[i][j] = fmaf(buf[kw + j], wv, acc[i][j]);
                }
            }
        }
    }

    // ---------------- epilogue: store ----------------
    const float b0  = bias[0];
    const int   ox0 = bx0 + lx0;
    const int   oy0 = by0 + ly0;
#pragma unroll
    for (int i = 0; i < TY; ++i) {
        const int oy = oy0 + i;
        if (oy < OH) {
            float* orow = &out[(size_t)oy * OW + ox0];
            if (ox0 + TX <= OW) {
                // OW=4082: (oy*OW + ox0)*4 is 8B-aligned (OW even, ox0 mult of 4)
                const float2 v0 = make_float2(acc[i][0] + b0, acc[i][1] + b0);
                const float2 v1 = make_float2(acc[i][2] + b0, acc[i][3] + b0);
                *reinterpret_cast<float2*>(&orow[0]) = v0;
                *reinterpret_cast<float2*>(&orow[2]) = v1;
            } else {
#pragma unroll
                for (int j = 0; j < TX; ++j)
                    if (ox0 + j < OW) orow[j] = acc[i][j] + b0;
            }
        }
    }
}

extern "C" void kernel_launch(void* const* d_in, const int* in_sizes, int n_in,
                              void* d_out, int out_size, void* d_ws, size_t ws_size,
                              hipStream_t stream) {
    const float* x    = (const float*)d_in[0];
    const float* w    = (const float*)d_in[1];
    const float* bias = (const float*)d_in[2];
    float* out        = (float*)d_out;

    dim3 grid((OW + BX - 1) / BX, (OH + BY - 1) / BY);  // 64 x 32
    dim3 block(256);
    conv2d_f32_tiled<<<grid, block, 0, stream>>>(x, w, bias, out);
}

// Round 2
// 155.514 us; speedup vs baseline: 1.3312x; 1.3312x over previous
//
#include <hip/hip_runtime.h>

// Conv2D 15x15 valid, 4096^2 fp32 -> 4082^2 fp32, via bf16 MFMA Toeplitz-band.
//
// Per kh: C[16x16] += A(16x32) * B(32x16) with A = x rows (bf16 LDS tile),
// B[k][n] = w[kh][k-n] band (0 outside). 15/32 band utilization, but raw
// MFMA rate (2 PF) makes this memory-bound: HBM ~140 MB -> ~22 us floor.
//
// Block: 256 thr = 4 waves, 64x64 output tile. Wave w: rows [16w,16w+16),
// 4 x-tiles of 16 cols. LDS: x-tile 78x80 bf16 (stride 88 = 176 B rows ->
// bank skew 12 dwords, 2-way max = free) + 15x64 B-fragment table. B frags
// live in 60 VGPRs across the kh loop; A frags: 1 ds_read_b128 per MFMA,
// all 60 reads off one base VGPR + immediate offsets.

#define HIN 4096
#define WIN 4096
#define KH 15
#define KW 15
#define OH (HIN - KH + 1)  // 4082
#define OW (WIN - KW + 1)  // 4082

#define BX 64
#define BY 64
#define XROWS (BY + KH - 1)     // 78 staged input rows
#define XCOLS 80                // staged input cols (64 + 14, padded to 80)
#define LDSW 88                 // bf16 row stride (176 B = 11*16 -> 16B-aligned, odd*16)
#define BTAB (XROWS * LDSW)     // 6864: short-index of B-frag table
#define NSH (BTAB + 15 * 64 * 8)  // 14544 shorts = 29088 B LDS

typedef short bf16x8 __attribute__((ext_vector_type(8)));
typedef float f32x4  __attribute__((ext_vector_type(4)));

static __device__ inline short f2bf(float f) {  // fp32 -> bf16 RNE
    unsigned u = __float_as_uint(f);
    u += 0x7fffu + ((u >> 16) & 1u);
    return (short)(u >> 16);
}

__global__ __launch_bounds__(256)
void conv2d_mfma(const float* __restrict__ x,
                 const float* __restrict__ w,
                 const float* __restrict__ bias,
                 float* __restrict__ out) {
    __shared__ short lds[NSH];

    const int tid = threadIdx.x;
    const int ox0 = blockIdx.x * BX;
    const int oy0 = blockIdx.y * BY;

    // ---------------- stage x tile: 78 x 80 fp32 -> bf16 LDS ----------------
    for (int f = tid; f < XROWS * (XCOLS / 4); f += 256) {
        const int r  = f / (XCOLS / 4);
        const int c4 = (f - r * (XCOLS / 4)) * 4;
        int gy = oy0 + r;
        if (gy > HIN - 1) gy = HIN - 1;   // clamped rows feed only masked outputs
        const int gx = ox0 + c4;
        float4 v;
        if (gx + 3 <= WIN - 1) {
            v = *reinterpret_cast<const float4*>(&x[(size_t)gy * WIN + gx]);
        } else {
            const float* row = &x[(size_t)gy * WIN];
            const int x0 = (gx + 0 > WIN - 1) ? WIN - 1 : gx + 0;
            const int x1 = (gx + 1 > WIN - 1) ? WIN - 1 : gx + 1;
            const int x2 = (gx + 2 > WIN - 1) ? WIN - 1 : gx + 2;
            const int x3 = (gx + 3 > WIN - 1) ? WIN - 1 : gx + 3;
            v = make_float4(row[x0], row[x1], row[x2], row[x3]);
        }
        short4 s;
        s.x = f2bf(v.x); s.y = f2bf(v.y); s.z = f2bf(v.z); s.w = f2bf(v.w);
        *reinterpret_cast<short4*>(&lds[r * LDSW + c4]) = s;   // ds_write_b64
    }

    // ------------- build B-fragment table: B[kh][k][n] = w[kh][k-n] -------------
    // Fragment layout for mfma_16x16x32 B-operand: lane L holds
    // B[k=(L>>4)*8+j][n=L&15], j=0..7.
    for (int e = tid; e < 15 * 64; e += 256) {
        const int kh = e >> 6;
        const int L  = e & 63;
        const int n  = L & 15;
        const int q  = L >> 4;
        bf16x8 bv;
#pragma unroll
        for (int j = 0; j < 8; ++j) {
            const int d = q * 8 + j - n;          // k - n
            bv[j] = (d >= 0 && d < KW) ? f2bf(w[kh * KW + d]) : (short)0;
        }
        *reinterpret_cast<bf16x8*>(&lds[BTAB + e * 8]) = bv;
    }
    __syncthreads();

    // ---------------- compute: 15 kh x 4 x-tiles of 16x16 MFMA ----------------
    const int lane = tid & 63;
    const int wv   = tid >> 6;        // wave id 0..3 -> output rows [16*wv, +16)
    const int m    = lane & 15;       // A-row (and D-col) index
    const int q    = lane >> 4;       // quad

    bf16x8 B[KH];
#pragma unroll
    for (int kh = 0; kh < KH; ++kh)
        B[kh] = *reinterpret_cast<const bf16x8*>(&lds[BTAB + (kh * 64 + lane) * 8]);

    f32x4 acc[4];
#pragma unroll
    for (int t = 0; t < 4; ++t) acc[t] = (f32x4){0.f, 0.f, 0.f, 0.f};

    // A-frag base: row (16*wv + m), col q*8 ; offsets kh*LDSW + t*16 are imm-friendly
    const short* abase = &lds[(wv * 16 + m) * LDSW + q * 8];
#pragma unroll
    for (int kh = 0; kh < KH; ++kh) {
#pragma unroll
        for (int t = 0; t < 4; ++t) {
            const bf16x8 a =
                *reinterpret_cast<const bf16x8*>(abase + kh * LDSW + t * 16);  // ds_read_b128
            acc[t] = __builtin_amdgcn_mfma_f32_16x16x32_bf16(a, B[kh], acc[t], 0, 0, 0);
        }
    }

    // ---------------- epilogue: D layout col=lane&15, row=q*4+reg ----------------
    const float b0 = bias[0];
    const int row0 = oy0 + wv * 16 + q * 4;
#pragma unroll
    for (int t = 0; t < 4; ++t) {
        const int col = ox0 + t * 16 + m;
        if (col < OW) {
#pragma unroll
            for (int r = 0; r < 4; ++r) {
                const int row = row0 + r;
                if (row < OH)
                    out[(size_t)row * OW + col] = acc[t][r] + b0;
            }
        }
    }
}

extern "C" void kernel_launch(void* const* d_in, const int* in_sizes, int n_in,
                              void* d_out, int out_size, void* d_ws, size_t ws_size,
                              hipStream_t stream) {
    const float* x    = (const float*)d_in[0];
    const float* w    = (const float*)d_in[1];
    const float* bias = (const float*)d_in[2];
    float* out        = (float*)d_out;

    dim3 grid((OW + BX - 1) / BX, (OH + BY - 1) / BY);  // 64 x 64
    dim3 block(256);
    conv2d_mfma<<<grid, block, 0, stream>>>(x, w, bias, out);
}